// Round 1
// baseline (115.261 us; speedup 1.0000x reference)
//
#include <hip/hip_runtime.h>

#define NPTS 16384
#define NSPLIT 16
#define CHUNK (NPTS / NSPLIT)   // 1024 sources per chunk
#define TBLK (NPTS / 512)       // 32 target blocks (2 targets per thread)

// Kernel 1: per (target-block, source-chunk) partial argmin.
// LDS stages chunk as {-2x, -2y, -2z, ||s||^2} so d2 = fma chain (3 FMA/pair).
__global__ __launch_bounds__(256) void nn_partial(const float* __restrict__ src,
                                                  const float* __restrict__ tar,
                                                  float2* __restrict__ ws) {
    __shared__ float4 sp[CHUNK];
    const int tid = threadIdx.x;
    const int tb  = blockIdx.x;
    const int sc  = blockIdx.y;
    const int sbase = sc * CHUNK;

    for (int i = tid; i < CHUNK; i += 256) {
        float x = src[(sbase + i) * 3 + 0];
        float y = src[(sbase + i) * 3 + 1];
        float z = src[(sbase + i) * 3 + 2];
        sp[i] = make_float4(-2.0f * x, -2.0f * y, -2.0f * z, x * x + y * y + z * z);
    }
    __syncthreads();

    const int t0 = tb * 512 + tid;
    const int t1 = t0 + 256;
    const float tx0 = tar[t0 * 3 + 0], ty0 = tar[t0 * 3 + 1], tz0 = tar[t0 * 3 + 2];
    const float tx1 = tar[t1 * 3 + 0], ty1 = tar[t1 * 3 + 1], tz1 = tar[t1 * 3 + 2];

    float best0 = 1e30f, best1 = 1e30f;
    int bi0 = 0, bi1 = 0;
#pragma unroll 4
    for (int j = 0; j < CHUNK; ++j) {
        float4 s = sp[j];
        float d0 = fmaf(tx0, s.x, fmaf(ty0, s.y, fmaf(tz0, s.z, s.w)));
        float d1 = fmaf(tx1, s.x, fmaf(ty1, s.y, fmaf(tz1, s.z, s.w)));
        if (d0 < best0) { best0 = d0; bi0 = j; }   // strict <  => first min (np.argmin)
        if (d1 < best1) { best1 = d1; bi1 = j; }
    }
    ws[sc * NPTS + t0] = make_float2(best0, __int_as_float(sbase + bi0));
    ws[sc * NPTS + t1] = make_float2(best1, __int_as_float(sbase + bi1));
}

// Kernel 2: reduce the NSPLIT partials per target, gather winner, accumulate loss.
__global__ __launch_bounds__(256) void nn_finish(const float* __restrict__ src,
                                                 const float* __restrict__ tar,
                                                 const float2* __restrict__ ws,
                                                 float* __restrict__ out) {
    const int t = blockIdx.x * 256 + threadIdx.x;
    float best = 1e30f;
    int bi = 0;
    for (int sc = 0; sc < NSPLIT; ++sc) {        // ascending chunk => lowest index wins ties
        float2 e = ws[sc * NPTS + t];
        if (e.x < best) { best = e.x; bi = __float_as_int(e.y); }
    }
    const float tx = tar[t * 3 + 0], ty = tar[t * 3 + 1], tz = tar[t * 3 + 2];
    const float dx = src[bi * 3 + 0] - tx;
    const float dy = src[bi * 3 + 1] - ty;
    const float dz = src[bi * 3 + 2] - tz;
    float v = 0.5f * (dx * dx + dy * dy + dz * dz);

    // wave64 shuffle reduction
    for (int off = 32; off > 0; off >>= 1) v += __shfl_down(v, off, 64);
    __shared__ float wsum[4];
    const int lane = threadIdx.x & 63, wv = threadIdx.x >> 6;
    if (lane == 0) wsum[wv] = v;
    __syncthreads();
    if (threadIdx.x == 0) atomicAdd(out, wsum[0] + wsum[1] + wsum[2] + wsum[3]);
}

// Fallback if d_ws is too small: single kernel, 64 blocks, full source sweep in LDS tiles.
__global__ __launch_bounds__(256) void nn_all(const float* __restrict__ src,
                                              const float* __restrict__ tar,
                                              float* __restrict__ out) {
    __shared__ float4 sp[2048];
    const int tid = threadIdx.x;
    const int t = blockIdx.x * 256 + tid;
    const float tx = tar[t * 3 + 0], ty = tar[t * 3 + 1], tz = tar[t * 3 + 2];
    float best = 1e30f;
    int bi = 0;
    for (int base = 0; base < NPTS; base += 2048) {
        __syncthreads();
        for (int i = tid; i < 2048; i += 256) {
            float x = src[(base + i) * 3 + 0];
            float y = src[(base + i) * 3 + 1];
            float z = src[(base + i) * 3 + 2];
            sp[i] = make_float4(-2.0f * x, -2.0f * y, -2.0f * z, x * x + y * y + z * z);
        }
        __syncthreads();
#pragma unroll 4
        for (int j = 0; j < 2048; ++j) {
            float4 s = sp[j];
            float d = fmaf(tx, s.x, fmaf(ty, s.y, fmaf(tz, s.z, s.w)));
            if (d < best) { best = d; bi = base + j; }
        }
    }
    const float dx = src[bi * 3 + 0] - tx;
    const float dy = src[bi * 3 + 1] - ty;
    const float dz = src[bi * 3 + 2] - tz;
    float v = 0.5f * (dx * dx + dy * dy + dz * dz);
    for (int off = 32; off > 0; off >>= 1) v += __shfl_down(v, off, 64);
    __shared__ float wsum[4];
    const int lane = threadIdx.x & 63, wv = threadIdx.x >> 6;
    if (lane == 0) wsum[wv] = v;
    __syncthreads();
    if (threadIdx.x == 0) atomicAdd(out, wsum[0] + wsum[1] + wsum[2] + wsum[3]);
}

extern "C" void kernel_launch(void* const* d_in, const int* in_sizes, int n_in,
                              void* d_out, int out_size, void* d_ws, size_t ws_size,
                              hipStream_t stream) {
    const float* src = (const float*)d_in[0];
    const float* tar = (const float*)d_in[1];
    float* out = (float*)d_out;

    hipMemsetAsync(d_out, 0, sizeof(float) * (size_t)out_size, stream);

    const size_t need = (size_t)NSPLIT * NPTS * sizeof(float2);
    if (ws_size >= need) {
        nn_partial<<<dim3(TBLK, NSPLIT), 256, 0, stream>>>(src, tar, (float2*)d_ws);
        nn_finish<<<NPTS / 256, 256, 0, stream>>>(src, tar, (const float2*)d_ws, out);
    } else {
        nn_all<<<NPTS / 256, 256, 0, stream>>>(src, tar, out);
    }
}

// Round 2
// 82.850 us; speedup vs baseline: 1.3912x; 1.3912x over previous
//
#include <hip/hip_runtime.h>

#define NPTS 16384
#define NSPLIT 32
#define CHUNK (NPTS / NSPLIT)        // 512 sources per chunk
#define TPT 4                        // targets per thread
#define TBLK (NPTS / (256 * TPT))    // 16 target blocks

// Kernel 1: per (target-block, source-chunk) partial MIN of d2 = ||s||^2 - 2 t.s.
// No index tracking: loss only needs min distance (see launch_launch comment).
// LDS stages chunk as {-2x, -2y, -2z, ||s||^2}; d2 = 3-FMA chain; min = v_min_f32.
__global__ __launch_bounds__(256) void nn_min(const float* __restrict__ src,
                                              const float* __restrict__ tar,
                                              float* __restrict__ ws) {
    __shared__ float4 sp[CHUNK];
    const int tid = threadIdx.x;
    const int tb  = blockIdx.x;
    const int sc  = blockIdx.y;
    const int sbase = sc * CHUNK;

    for (int i = tid; i < CHUNK; i += 256) {
        float x = src[(sbase + i) * 3 + 0];
        float y = src[(sbase + i) * 3 + 1];
        float z = src[(sbase + i) * 3 + 2];
        sp[i] = make_float4(-2.0f * x, -2.0f * y, -2.0f * z, x * x + y * y + z * z);
    }
    __syncthreads();

    const int t0 = tb * (256 * TPT) + tid;
    float tx[TPT], ty[TPT], tz[TPT], best[TPT];
#pragma unroll
    for (int k = 0; k < TPT; ++k) {
        const int t = t0 + k * 256;
        tx[k] = tar[t * 3 + 0];
        ty[k] = tar[t * 3 + 1];
        tz[k] = tar[t * 3 + 2];
        best[k] = 1e30f;
    }

#pragma unroll 4
    for (int j = 0; j < CHUNK; ++j) {
        float4 s = sp[j];
#pragma unroll
        for (int k = 0; k < TPT; ++k) {
            float d = fmaf(tx[k], s.x, fmaf(ty[k], s.y, fmaf(tz[k], s.z, s.w)));
            best[k] = fminf(best[k], d);
        }
    }
#pragma unroll
    for (int k = 0; k < TPT; ++k)
        ws[sc * NPTS + t0 + k * 256] = best[k];
}

// Kernel 2: reduce NSPLIT partial mins per target, add ||t||^2, sum 0.5*d2 into out.
__global__ __launch_bounds__(256) void nn_sum(const float* __restrict__ tar,
                                              const float* __restrict__ ws,
                                              float* __restrict__ out) {
    const int t = blockIdx.x * 256 + threadIdx.x;
    float best = 1e30f;
#pragma unroll
    for (int sc = 0; sc < NSPLIT; ++sc)
        best = fminf(best, ws[sc * NPTS + t]);
    const float tx = tar[t * 3 + 0], ty = tar[t * 3 + 1], tz = tar[t * 3 + 2];
    float v = 0.5f * (best + tx * tx + ty * ty + tz * tz);   // 0.5*||t-s||^2

    for (int off = 32; off > 0; off >>= 1) v += __shfl_down(v, off, 64);
    __shared__ float wsum[4];
    const int lane = threadIdx.x & 63, wv = threadIdx.x >> 6;
    if (lane == 0) wsum[wv] = v;
    __syncthreads();
    if (threadIdx.x == 0) atomicAdd(out, wsum[0] + wsum[1] + wsum[2] + wsum[3]);
}

// Fallback if d_ws is too small (not expected; ws need == 2 MB, proven to fit):
// single kernel, full source sweep in LDS tiles, min-only.
__global__ __launch_bounds__(256) void nn_all(const float* __restrict__ src,
                                              const float* __restrict__ tar,
                                              float* __restrict__ out) {
    __shared__ float4 sp[2048];
    const int tid = threadIdx.x;
    const int t = blockIdx.x * 256 + tid;
    const float tx = tar[t * 3 + 0], ty = tar[t * 3 + 1], tz = tar[t * 3 + 2];
    float best = 1e30f;
    for (int base = 0; base < NPTS; base += 2048) {
        __syncthreads();
        for (int i = tid; i < 2048; i += 256) {
            float x = src[(base + i) * 3 + 0];
            float y = src[(base + i) * 3 + 1];
            float z = src[(base + i) * 3 + 2];
            sp[i] = make_float4(-2.0f * x, -2.0f * y, -2.0f * z, x * x + y * y + z * z);
        }
        __syncthreads();
#pragma unroll 4
        for (int j = 0; j < 2048; ++j) {
            float4 s = sp[j];
            float d = fmaf(tx, s.x, fmaf(ty, s.y, fmaf(tz, s.z, s.w)));
            best = fminf(best, d);
        }
    }
    float v = 0.5f * (best + tx * tx + ty * ty + tz * tz);
    for (int off = 32; off > 0; off >>= 1) v += __shfl_down(v, off, 64);
    __shared__ float wsum[4];
    const int lane = threadIdx.x & 63, wv = threadIdx.x >> 6;
    if (lane == 0) wsum[wv] = v;
    __syncthreads();
    if (threadIdx.x == 0) atomicAdd(out, wsum[0] + wsum[1] + wsum[2] + wsum[3]);
}

extern "C" void kernel_launch(void* const* d_in, const int* in_sizes, int n_in,
                              void* d_out, int out_size, void* d_ws, size_t ws_size,
                              hipStream_t stream) {
    const float* src = (const float*)d_in[0];
    const float* tar = (const float*)d_in[1];
    float* out = (float*)d_out;

    hipMemsetAsync(d_out, 0, sizeof(float) * (size_t)out_size, stream);

    const size_t need = (size_t)NSPLIT * NPTS * sizeof(float);   // 2 MB
    if (ws_size >= need) {
        nn_min<<<dim3(TBLK, NSPLIT), 256, 0, stream>>>(src, tar, (float*)d_ws);
        nn_sum<<<NPTS / 256, 256, 0, stream>>>(tar, (const float*)d_ws, out);
    } else {
        nn_all<<<NPTS / 256, 256, 0, stream>>>(src, tar, out);
    }
}